// Round 1
// baseline (548.263 us; speedup 1.0000x reference)
//
#include <hip/hip_runtime.h>
#include <math.h>

#define SB 64
#define SS 512
#define SH 768
#define NT 36
#define TSTART 34
#define TSTOP 35

__device__ __forceinline__ float wave_max_f(float v) {
#pragma unroll
    for (int off = 32; off > 0; off >>= 1) v = fmaxf(v, __shfl_xor(v, off, 64));
    return v;
}
__device__ __forceinline__ float wave_sum_f(float v) {
#pragma unroll
    for (int off = 32; off > 0; off >>= 1) v += __shfl_xor(v, off, 64);
    return v;
}

// ---------------- emissions: logits = leaky_relu(gather(x) @ W + b) ----------------
// grid: 512 blocks x 256 threads. Each block: 64 rows. Wave w handles tags [9w, 9w+9).
extern "C" __global__ __launch_bounds__(256) void k_emit(
    const float* __restrict__ x1, const int* __restrict__ hidx,
    const float* __restrict__ W, const float* __restrict__ bias,
    float* __restrict__ emit)
{
    int tid  = threadIdx.x;
    int lane = tid & 63;
    int grp  = __builtin_amdgcn_readfirstlane(tid >> 6);   // wave-uniform tag group
    int gr   = blockIdx.x * 64 + lane;                     // global row in [0, B*S)
    int b    = gr >> 9;
    int hi   = hidx[gr];
    const float4* xr = (const float4*)(x1 + (size_t)(b * SS + hi) * SH);
    int j0 = grp * 9;
    float acc[9];
#pragma unroll
    for (int j = 0; j < 9; ++j) acc[j] = 0.f;
    const float* Wp = W + j0;
    for (int h4 = 0; h4 < SH / 4; ++h4) {
        float4 xv = xr[h4];
        const float* w0 = Wp + (h4 * 4) * NT;   // wave-uniform address -> scalar loads
#pragma unroll
        for (int j = 0; j < 9; ++j) acc[j] += xv.x * w0[j];
#pragma unroll
        for (int j = 0; j < 9; ++j) acc[j] += xv.y * w0[NT + j];
#pragma unroll
        for (int j = 0; j < 9; ++j) acc[j] += xv.z * w0[2 * NT + j];
#pragma unroll
        for (int j = 0; j < 9; ++j) acc[j] += xv.w * w0[3 * NT + j];
    }
    float* op = emit + (size_t)gr * NT + j0;
#pragma unroll
    for (int j = 0; j < 9; ++j) {
        float v = acc[j] + bias[j0 + j];
        op[j] = v > 0.f ? v : 0.01f * v;
    }
}

// ---------------- CRF: blocks 0..63 forward NLL, 64..127 viterbi ----------------
extern "C" __global__ __launch_bounds__(64) void k_crf(
    const float* __restrict__ emit, const int* __restrict__ hidx,
    const int* __restrict__ tags, const float* __restrict__ trans,
    float* __restrict__ lossp, float* __restrict__ path_out,
    float* __restrict__ score_out)
{
    __shared__ float trl[NT * NT];
    __shared__ int   bp[SS * NT];
    __shared__ int   pathl[SS];

    int lane  = threadIdx.x;
    int b     = blockIdx.x & 63;
    bool vit  = blockIdx.x >= 64;

    for (int i = lane; i < NT * NT; i += 64) trl[i] = trans[i];

    // xlen = max(head_indexes[b, :])
    int xm = 0;
    const int* hb = hidx + b * SS;
#pragma unroll
    for (int k = 0; k < SS / 64; ++k) xm = max(xm, hb[lane + 64 * k]);
#pragma unroll
    for (int off = 32; off > 0; off >>= 1) xm = max(xm, __shfl_xor(xm, off, 64));
    int xlen = xm;
    __syncthreads();

    int  j   = lane < NT ? lane : NT - 1;
    bool act = lane < NT;
    const float* eb = emit + (size_t)b * SS * NT;

    if (!vit) {
        // ---------- forward (logsumexp recurrence) ----------
        float Ecol[NT];
#pragma unroll
        for (int i = 0; i < NT; ++i) Ecol[i] = __expf(trl[i * NT + j]);
        float tstop = trl[j * NT + TSTOP];
        float alpha = act ? (eb[j] + trl[TSTART * NT + j]) : -1e30f;
        float ecur  = eb[NT + j];
        for (int t = 1; t < xlen; ++t) {
            float enext = eb[(size_t)(t + 1) * NT + j];   // t+1 <= 511, in-bounds
            float m = wave_max_f(alpha);
            float p = __expf(alpha - m);
            float s0 = 0.f, s1 = 0.f, s2 = 0.f, s3 = 0.f;
#pragma unroll
            for (int i = 0; i < NT; i += 4) {
                s0 += __shfl(p, i,     64) * Ecol[i];
                s1 += __shfl(p, i + 1, 64) * Ecol[i + 1];
                s2 += __shfl(p, i + 2, 64) * Ecol[i + 2];
                s3 += __shfl(p, i + 3, 64) * Ecol[i + 3];
            }
            float anew = m + __logf((s0 + s1) + (s2 + s3)) + ecur;
            alpha = act ? anew : -1e30f;
            ecur = enext;
        }
        float f = act ? (alpha + tstop) : -1e30f;
        float M = wave_max_f(f);
        float ssum = wave_sum_f(__expf(f - M));
        float logZ = M + __logf(ssum);
        // gold score
        const int* tg = tags + b * SS;
        float g = 0.f;
        for (int t = lane; t < SS; t += 64) {
            if (t < xlen) {
                int tt = tg[t];
                g += eb[(size_t)t * NT + tt];
                if (t >= 1) g += trl[tg[t - 1] * NT + tt];
            }
        }
        g = wave_sum_f(g);
        if (lane == 0) {
            int lt = (xlen >= 1) ? tg[xlen - 1] : tg[0];
            float gold = g + trl[TSTART * NT + tg[0]] + trl[lt * NT + TSTOP];
            lossp[b] = logZ - gold;
        }
    } else {
        // ---------- viterbi ----------
        float tcol[NT];
#pragma unroll
        for (int i = 0; i < NT; ++i) tcol[i] = trl[i * NT + j];
        float tstop = trl[j * NT + TSTOP];
        float delta = act ? (eb[j] + trl[TSTART * NT + j]) : -1e30f;
        float ecur  = eb[NT + j];
        for (int t = 1; t < xlen; ++t) {
            float enext = eb[(size_t)(t + 1) * NT + j];
            float b0 = -1e30f, b1 = -1e30f, b2 = -1e30f, b3 = -1e30f;
            int   i0 = 0, i1 = 9, i2 = 18, i3 = 27;
#pragma unroll
            for (int i = 0; i < 9; ++i) {
                float a0 = __shfl(delta, i,      64) + tcol[i];
                float a1 = __shfl(delta, i + 9,  64) + tcol[i + 9];
                float a2 = __shfl(delta, i + 18, 64) + tcol[i + 18];
                float a3 = __shfl(delta, i + 27, 64) + tcol[i + 27];
                if (a0 > b0) { b0 = a0; i0 = i; }
                if (a1 > b1) { b1 = a1; i1 = i + 9; }
                if (a2 > b2) { b2 = a2; i2 = i + 18; }
                if (a3 > b3) { b3 = a3; i3 = i + 27; }
            }
            // combine left-to-right with strict > : preserves first-index tie-break
            float best = b0; int bi = i0;
            if (b1 > best) { best = b1; bi = i1; }
            if (b2 > best) { best = b2; bi = i2; }
            if (b3 > best) { best = b3; bi = i3; }
            float dnew = best + ecur;
            delta = act ? dnew : -1e30f;
            if (act) bp[t * NT + j] = bi;
            ecur = enext;
        }
        float f = act ? (delta + tstop) : -1e30f;
        float bv = f; int bi = lane;   // inactive lanes: -1e30 with large idx
#pragma unroll
        for (int off = 32; off > 0; off >>= 1) {
            float ov = __shfl_xor(bv, off, 64);
            int   oi = __shfl_xor(bi, off, 64);
            if (ov > bv || (ov == bv && oi < bi)) { bv = ov; bi = oi; }
        }
        int last_tag = bi;
        if (lane == 0) score_out[b] = bv;
        __syncthreads();
        if (lane == 0 && xlen >= 1) pathl[xlen - 1] = last_tag;
        // backtrack: chase via cross-lane shuffle (bp row loads are chain-independent)
        int v = last_tag;
        for (int t = xlen - 1; t >= 1; --t) {
            int bpv = bp[t * NT + j];
            v = __shfl(bpv, v, 64);
            if (lane == 0) pathl[t - 1] = v;
        }
        __syncthreads();
        float* op = path_out + (size_t)b * SS;
        for (int t = lane; t < SS; t += 64)
            op[t] = (t < xlen) ? (float)pathl[t] : 0.0f;
    }
}

// ---------------- final loss reduction ----------------
extern "C" __global__ __launch_bounds__(64) void k_loss(
    const float* __restrict__ lossp, float* __restrict__ out)
{
    float v = lossp[threadIdx.x];
    v = wave_sum_f(v);
    if (threadIdx.x == 0) out[0] = v;
}

extern "C" void kernel_launch(void* const* d_in, const int* in_sizes, int n_in,
                              void* d_out, int out_size, void* d_ws, size_t ws_size,
                              hipStream_t stream)
{
    const float* x1    = (const float*)d_in[0];
    const int*   hidx  = (const int*)d_in[1];
    const int*   tags  = (const int*)d_in[2];
    const float* W     = (const float*)d_in[3];
    const float* bias  = (const float*)d_in[4];
    const float* trans = (const float*)d_in[5];
    float* out   = (float*)d_out;
    float* emit  = (float*)d_ws;                       // B*S*NT floats = 4.72 MB
    float* lossp = emit + (size_t)SB * SS * NT;        // +64 floats

    hipLaunchKernelGGL(k_emit, dim3(SB * SS / 64), dim3(256), 0, stream,
                       x1, hidx, W, bias, emit);
    hipLaunchKernelGGL(k_crf, dim3(128), dim3(64), 0, stream,
                       emit, hidx, tags, trans, lossp, out + 1, out + 1 + SB * SS);
    hipLaunchKernelGGL(k_loss, dim3(1), dim3(64), 0, stream, lossp, out);
}

// Round 2
// 531.502 us; speedup vs baseline: 1.0315x; 1.0315x over previous
//
#include <hip/hip_runtime.h>
#include <math.h>

#define SB 64
#define SS 512
#define SH 768
#define NT 36
#define TSTART 34
#define TSTOP 35

#define CFENCE() asm volatile("" ::: "memory")

__device__ __forceinline__ float wave_max_f(float v) {
#pragma unroll
    for (int off = 32; off > 0; off >>= 1) v = fmaxf(v, __shfl_xor(v, off, 64));
    return v;
}
__device__ __forceinline__ float wave_sum_f(float v) {
#pragma unroll
    for (int off = 32; off > 0; off >>= 1) v += __shfl_xor(v, off, 64);
    return v;
}
__device__ __forceinline__ float bcast0(float v) {
    return __uint_as_float(__builtin_amdgcn_readfirstlane(__float_as_uint(v)));
}

// ---------------- emissions: logits = leaky_relu(gather(x) @ W + b) ----------------
// 512 blocks x 256 threads. Block owns 64 rows (row = lane). Wave w computes tags
// [9w, 9w+9). Rows staged via async global_load_lds (16B/lane gather) into LDS,
// double-buffered; compute reads are contiguous conflict-free ds_read_b128.
extern "C" __global__ __launch_bounds__(256) void k_emit(
    const float* __restrict__ x1, const int* __restrict__ hidx,
    const float* __restrict__ W, const float* __restrict__ bias,
    float* __restrict__ emit)
{
    __shared__ float4 xs4[2][32][64];   // [buf][h4-slot][row], 64 KB

    int tid  = threadIdx.x;
    int lane = tid & 63;
    int w    = __builtin_amdgcn_readfirstlane(tid >> 6);
    int gr   = blockIdx.x * 64 + lane;           // row handled by this lane (all waves)
    int b    = gr >> 9;
    int hi   = hidx[gr];
    const float* xb = x1 + (size_t)(b * SS + hi) * SH;   // per-lane gather base

    // stage chunk c (128 h-values = 32 float4-slots) into buffer f.
    // wave w stages slots [8w, 8w+8): per slot one async 16B/lane gather.
    auto stage = [&](int c, int f) {
#pragma unroll
        for (int s = 0; s < 8; ++s) {
            int h4 = w * 8 + s;
            __builtin_amdgcn_global_load_lds(
                (const __attribute__((address_space(1))) void*)(xb + (size_t)(c * 128 + h4 * 4)),
                (__attribute__((address_space(3))) void*)&xs4[f][h4][0],
                16, 0, 0);
        }
    };

    int j0 = w * 9;
    float acc[9];
#pragma unroll
    for (int j = 0; j < 9; ++j) acc[j] = 0.f;

    stage(0, 0);
    int f = 0;
    for (int c = 0; c < 6; ++c) {
        __syncthreads();                  // staging of chunk c complete; buffers safe
        if (c < 5) stage(c + 1, f ^ 1);   // async prefetch next chunk
        const float* Wc = W + (size_t)(c * 128) * NT + j0;
#pragma unroll 4
        for (int h4 = 0; h4 < 32; ++h4) {
            float4 xv = xs4[f][h4][lane];
            const float* w0 = Wc + (size_t)(h4 * 4) * NT;  // wave-uniform -> s_load
#pragma unroll
            for (int j = 0; j < 9; ++j) acc[j] += xv.x * w0[j];
#pragma unroll
            for (int j = 0; j < 9; ++j) acc[j] += xv.y * w0[NT + j];
#pragma unroll
            for (int j = 0; j < 9; ++j) acc[j] += xv.z * w0[2 * NT + j];
#pragma unroll
            for (int j = 0; j < 9; ++j) acc[j] += xv.w * w0[3 * NT + j];
        }
        f ^= 1;
    }

    float* op = emit + (size_t)gr * NT + j0;
#pragma unroll
    for (int j = 0; j < 9; ++j) {
        float v = acc[j] + bias[j0 + j];
        op[j] = v > 0.f ? v : 0.01f * v;
    }
}

// ---------------- CRF: blocks 0..63 forward NLL, 64..127 viterbi ----------------
extern "C" __global__ __launch_bounds__(64) void k_crf(
    const float* __restrict__ emit, const int* __restrict__ hidx,
    const int* __restrict__ tags, const float* __restrict__ trans,
    float* __restrict__ lossp, float* __restrict__ path_out,
    float* __restrict__ score_out)
{
    __shared__ float trl[NT * NT];
    __shared__ float4 bcast4[16];        // 64-float wave broadcast buffer
    __shared__ int   bp[SS * NT];
    __shared__ int   pathl[SS];

    int lane  = threadIdx.x;
    int b     = blockIdx.x & 63;
    bool vit  = blockIdx.x >= 64;
    float* bc = (float*)bcast4;

    for (int i = lane; i < NT * NT; i += 64) trl[i] = trans[i];

    // xlen = max(head_indexes[b, :])
    int xm = 0;
    const int* hb = hidx + b * SS;
#pragma unroll
    for (int k = 0; k < SS / 64; ++k) xm = max(xm, hb[lane + 64 * k]);
#pragma unroll
    for (int off = 32; off > 0; off >>= 1) xm = max(xm, __shfl_xor(xm, off, 64));
    int xlen = xm;
    __syncthreads();

    int  j   = lane < NT ? lane : NT - 1;
    bool act = lane < NT;
    const float* eb = emit + (size_t)b * SS * NT;

    if (!vit) {
        // ---------- forward (shifted-exp logsumexp recurrence) ----------
        float Ecol[NT];
#pragma unroll
        for (int i = 0; i < NT; ++i) Ecol[i] = __expf(trl[i * NT + j]);
        float tstop = trl[j * NT + TSTOP];
        float alpha = act ? (eb[j] + trl[TSTART * NT + j]) : -1e30f;
        float ecur  = eb[NT + j];
        for (int t = 1; t < xlen; ++t) {
            float enext = eb[(size_t)(t + 1) * NT + j];
            float m = bcast0(alpha);            // SALU broadcast; tag-spread bounded
            float p = __expf(alpha - m);        // inactive lanes -> exp(-1e30)=0
            bc[lane] = p;
            CFENCE();
            __builtin_amdgcn_wave_barrier();    // same-wave DS ops are in-order
            float s0 = 0.f, s1 = 0.f, s2 = 0.f, s3 = 0.f;
#pragma unroll
            for (int k = 0; k < 9; ++k) {
                float4 pv = bcast4[k];          // broadcast read, conflict-free
                s0 += pv.x * Ecol[4 * k];
                s1 += pv.y * Ecol[4 * k + 1];
                s2 += pv.z * Ecol[4 * k + 2];
                s3 += pv.w * Ecol[4 * k + 3];
            }
            CFENCE();
            float anew = m + __logf((s0 + s1) + (s2 + s3)) + ecur;
            alpha = act ? anew : -1e30f;
            ecur = enext;
        }
        float ff = act ? (alpha + tstop) : -1e30f;
        float M = wave_max_f(ff);
        float ssum = wave_sum_f(__expf(ff - M));
        float logZ = M + __logf(ssum);
        // gold score
        const int* tg = tags + b * SS;
        float g = 0.f;
        for (int t = lane; t < SS; t += 64) {
            if (t < xlen) {
                int tt = tg[t];
                g += eb[(size_t)t * NT + tt];
                if (t >= 1) g += trl[tg[t - 1] * NT + tt];
            }
        }
        g = wave_sum_f(g);
        if (lane == 0) {
            int lt = (xlen >= 1) ? tg[xlen - 1] : tg[0];
            float gold = g + trl[TSTART * NT + tg[0]] + trl[lt * NT + TSTOP];
            lossp[b] = logZ - gold;
        }
    } else {
        // ---------- viterbi ----------
        float tcol[NT];
#pragma unroll
        for (int i = 0; i < NT; ++i) tcol[i] = trl[i * NT + j];
        float tstop = trl[j * NT + TSTOP];
        float delta = act ? (eb[j] + trl[TSTART * NT + j]) : -1e30f;
        float ecur  = eb[NT + j];
        for (int t = 1; t < xlen; ++t) {
            float enext = eb[(size_t)(t + 1) * NT + j];
            bc[lane] = delta;
            CFENCE();
            __builtin_amdgcn_wave_barrier();
            float b0 = -1e30f, b1 = -1e30f, b2 = -1e30f, b3 = -1e30f;
            int   i0 = 0, i1 = 1, i2 = 2, i3 = 3;
#pragma unroll
            for (int k = 0; k < 9; ++k) {
                float4 dv = bcast4[k];
                float c0 = dv.x + tcol[4 * k];
                float c1 = dv.y + tcol[4 * k + 1];
                float c2 = dv.z + tcol[4 * k + 2];
                float c3 = dv.w + tcol[4 * k + 3];
                if (c0 > b0) { b0 = c0; i0 = 4 * k; }
                if (c1 > b1) { b1 = c1; i1 = 4 * k + 1; }
                if (c2 > b2) { b2 = c2; i2 = 4 * k + 2; }
                if (c3 > b3) { b3 = c3; i3 = 4 * k + 3; }
            }
            CFENCE();
            // combine interleaved chains with exact first-index tie-break
            float best = b0; int bi = i0;
            if (b1 > best || (b1 == best && i1 < bi)) { best = b1; bi = i1; }
            if (b2 > best || (b2 == best && i2 < bi)) { best = b2; bi = i2; }
            if (b3 > best || (b3 == best && i3 < bi)) { best = b3; bi = i3; }
            float dnew = best + ecur;
            delta = act ? dnew : -1e30f;
            if (act) bp[t * NT + j] = bi;
            ecur = enext;
        }
        float ff = act ? (delta + tstop) : -1e30f;
        float bv = ff; int bi = lane;
#pragma unroll
        for (int off = 32; off > 0; off >>= 1) {
            float ov = __shfl_xor(bv, off, 64);
            int   oi = __shfl_xor(bi, off, 64);
            if (ov > bv || (ov == bv && oi < bi)) { bv = ov; bi = oi; }
        }
        int last_tag = bi;
        if (lane == 0) score_out[b] = bv;
        __syncthreads();
        if (lane == 0 && xlen >= 1) pathl[xlen - 1] = last_tag;
        int v = last_tag;
        for (int t = xlen - 1; t >= 1; --t) {
            int bpv = bp[t * NT + j];
            v = __shfl(bpv, v, 64);
            if (lane == 0) pathl[t - 1] = v;
        }
        __syncthreads();
        float* op = path_out + (size_t)b * SS;
        for (int t = lane; t < SS; t += 64)
            op[t] = (t < xlen) ? (float)pathl[t] : 0.0f;
    }
}

// ---------------- final loss reduction ----------------
extern "C" __global__ __launch_bounds__(64) void k_loss(
    const float* __restrict__ lossp, float* __restrict__ out)
{
    float v = lossp[threadIdx.x];
    v = wave_sum_f(v);
    if (threadIdx.x == 0) out[0] = v;
}

extern "C" void kernel_launch(void* const* d_in, const int* in_sizes, int n_in,
                              void* d_out, int out_size, void* d_ws, size_t ws_size,
                              hipStream_t stream)
{
    const float* x1    = (const float*)d_in[0];
    const int*   hidx  = (const int*)d_in[1];
    const int*   tags  = (const int*)d_in[2];
    const float* W     = (const float*)d_in[3];
    const float* bias  = (const float*)d_in[4];
    const float* trans = (const float*)d_in[5];
    float* out   = (float*)d_out;
    float* emit  = (float*)d_ws;                       // B*S*NT floats = 4.72 MB
    float* lossp = emit + (size_t)SB * SS * NT;        // +64 floats

    hipLaunchKernelGGL(k_emit, dim3(SB * SS / 64), dim3(256), 0, stream,
                       x1, hidx, W, bias, emit);
    hipLaunchKernelGGL(k_crf, dim3(128), dim3(64), 0, stream,
                       emit, hidx, tags, trans, lossp, out + 1, out + 1 + SB * SS);
    hipLaunchKernelGGL(k_loss, dim3(1), dim3(64), 0, stream, lossp, out);
}